// Round 6
// baseline (1792.569 us; speedup 1.0000x reference)
//
#include <hip/hip_runtime.h>
#include <stdint.h>

#define NIMG 512
#define CINCH 64
#define HIDC 128
#define NEDGE 16384
#define HWPIX 1024
#define PW2 34
#define PPIX 1156   // 34*34
#define RING 18
#define ROWB 8704   // 34 px * 256 B

typedef __attribute__((ext_vector_type(8))) short bf16x8;
typedef __attribute__((ext_vector_type(4))) float f32x4;

static __device__ __forceinline__ unsigned short f2bf(float f){
  unsigned u = __builtin_bit_cast(unsigned, f);
  u += 0x7FFFu + ((u>>16)&1u);
  return (unsigned short)(u>>16);
}
static __device__ __forceinline__ float bf2f(unsigned short s){
  unsigned u = ((unsigned)s)<<16;
  return __builtin_bit_cast(float, u);
}

// async 16B global->LDS (linear LDS dest; swizzle pre-applied on global src)
static __device__ __forceinline__ void gload16(const char* src, char* dst){
  __builtin_amdgcn_global_load_lds(
      (const __attribute__((address_space(1))) unsigned int*)src,
      (__attribute__((address_space(3))) unsigned int*)dst, 16, 0, 0);
}

// stage k rows starting at padded row R into ring (slots R%18.., no wrap by construction)
static __device__ __forceinline__ void stage_rows(char* lds_, const char* img,
                                                  int R, int ngr, int tid){
  int slot0 = R - (R >= RING ? RING : 0);
  char* dst0 = lds_ + slot0*ROWB;
  const char* src0 = img + (size_t)R*ROWB;
  #pragma unroll
  for(int it = 0; it*512 < 5440; ++it){
    if(it*512 >= ngr) break;
    int j = tid + it*512;
    if(j < ngr){
      int rl = j/544;             // row within span (34 px * 16 granules = 544)
      int i  = j - rl*544;
      int c  = i>>4, sl = i&15;
      int key = (R + rl + c) & 7;
      gload16(src0 + (size_t)rl*ROWB + c*256 + ((sl ^ key)<<4),
              dst0 + (size_t)j*16);
    }
  }
}

// ---------------- init: zero pad borders + accumulators + csr counters ------
__global__ void k_init(unsigned short* xe_pad, unsigned short* xp1_pad,
                       float* xnode_acc, int* cnt, int* pos){
  int idx = blockIdx.x*256 + threadIdx.x;
  int total_b = NIMG*132*16;
  for(int i = idx; i < total_b; i += gridDim.x*256){
    int img = i / (132*16);
    int rem = i - img*(132*16);
    int bp = rem >> 4;
    int slot = rem & 15;
    int r, c;
    if(bp < 34){ r = 0; c = bp; }
    else if(bp < 68){ r = 33; c = bp-34; }
    else if(bp < 100){ r = bp-68+1; c = 0; }
    else { r = bp-100+1; c = 33; }
    size_t off = ((size_t)img*PPIX + r*PW2 + c)*128 + slot*8;
    uint4 z = {0,0,0,0};
    *(uint4*)(xe_pad + off) = z;
    *(uint4*)(xp1_pad + off) = z;
  }
  for(int i = idx; i < NIMG*HIDC; i += gridDim.x*256) xnode_acc[i] = 0.f;
  for(int i = idx; i < NIMG; i += gridDim.x*256){ cnt[i] = 0; pos[i] = 0; }
}

// ---------------- weight conversion ------------------------------------------
// conv3 W layout (reg-direct): [tap][kc][co][fq][8] ; per (tap,kc,nf) a wave's
//   64 lanes read one contiguous 1KB burst. cin = kc*32 + fq*8 + j.
__global__ void k_wconv(const float* __restrict__ sp_w1, const float* __restrict__ sp_w2,
                        const float* __restrict__ fe_w, const float* __restrict__ op_w,
                        unsigned short* Wb1, unsigned short* Wb2,
                        unsigned short* Wfe, unsigned short* Wop){
  int idx = blockIdx.x*256 + threadIdx.x;
  for(int i = idx; i < 147456; i += gridDim.x*256){
    int j = i & 7, fq = (i>>3)&3, co = (i>>5)&127, kc = (i>>12)&3, tap = i>>14;
    int cin = kc*32 + fq*8 + j;
    Wb1[i] = f2bf(sp_w1[(co*128+cin)*9 + tap]);
    Wb2[i] = f2bf(sp_w2[(co*128+cin)*9 + tap]);
  }
  for(int i = idx; i < 8192; i += gridDim.x*256){
    int j = i & 7, s = (i>>3)&7, co = i>>6;
    int ci = ((s ^ (co&7))<<3) + j;
    Wfe[i] = f2bf(fe_w[co*64+ci]);
  }
  for(int i = idx; i < 8192; i += gridDim.x*256){
    int j = i & 7, s = (i>>3)&15, co = i>>7;   // co 0..63
    int cin = ((s ^ (co&7))<<3) + j;
    Wop[i] = f2bf(op_w[co*128+cin]);
  }
}

// ---------------- CSR build ------------------------------------------------
__global__ void k_csr_count(const int* __restrict__ ei, int* cnt){
  int e = blockIdx.x*256 + threadIdx.x;
  if(e < NEDGE) atomicAdd(&cnt[ei[NEDGE+e]], 1);
}
__global__ void k_csr_scan(const int* __restrict__ cnt, int* offs){
  __shared__ int sc[512];
  int t = threadIdx.x;
  sc[t] = cnt[t] + 1;   // +1 for self loop
  __syncthreads();
  for(int o = 1; o < 512; o <<= 1){
    int add = (t >= o) ? sc[t-o] : 0;
    __syncthreads();
    sc[t] += add;
    __syncthreads();
  }
  if(t == 0) offs[0] = 0;
  offs[t+1] = sc[t];
}
__global__ void k_csr_fill(const int* __restrict__ ei, const int* __restrict__ offs,
                           int* pos, int* csr_src){
  int e = blockIdx.x*256 + threadIdx.x;
  if(e < NEDGE + NIMG){
    int s, d;
    if(e < NEDGE){ s = ei[e]; d = ei[NEDGE+e]; }
    else { s = e - NEDGE; d = s; }
    int slot = offs[d] + atomicAdd(&pos[d], 1);
    csr_src[slot] = s;
  }
}

// ---------------- encode: 1x1 conv + BN + relu + conf, write padded NHWC ----
__launch_bounds__(256, 2)
__global__ void k_encode(const float* __restrict__ x, const float* __restrict__ conf,
                         const unsigned short* __restrict__ Wfe,
                         const float* __restrict__ fe_b, const float* __restrict__ fe_g,
                         const float* __restrict__ fe_beta,
                         unsigned short* __restrict__ xe_pad){
  __shared__ char lds[49152];          // xa 32KB (f32 swizzled) + wb 16KB
  char* xa = lds; char* wb = lds + 32768;
  int tid = threadIdx.x;
  int n = blockIdx.x >> 3, rg = blockIdx.x & 7;
  int hw0 = rg*128;
  {
    int q = tid >> 3, c0 = tid & 7;
    const float* xb = x + (size_t)n*CINCH*HWPIX + hw0;
    #pragma unroll
    for(int cc = 0; cc < 8; ++cc){
      int c = cc*8 + c0;
      float4 v = *(const float4*)(xb + (size_t)c*HWPIX + q*4);
      float vv[4] = {v.x, v.y, v.z, v.w};
      #pragma unroll
      for(int i = 0; i < 4; ++i){
        int p = q*4 + i;
        *(float*)(xa + p*256 + ((cc ^ (p&7))*32) + c0*4) = vv[i];
      }
    }
    #pragma unroll
    for(int it = 0; it < 4; ++it){
      uint4 w = *(const uint4*)((const char*)Wfe + it*4096 + tid*16);
      *(uint4*)(wb + it*4096 + tid*16) = w;
    }
  }
  __syncthreads();
  int wid = tid>>6, lane = tid&63;
  int wr = wid>>1, wc = wid&1, fr = lane&15, fq = lane>>4;
  f32x4 acc[4][4];
  #pragma unroll
  for(int a = 0; a < 4; ++a)
    #pragma unroll
    for(int b = 0; b < 4; ++b) acc[a][b] = (f32x4){0.f,0.f,0.f,0.f};
  #pragma unroll
  for(int kc = 0; kc < 2; ++kc){
    bf16x8 af[4], bfr[4];
    #pragma unroll
    for(int mi = 0; mi < 4; ++mi){
      int p = wr*64 + mi*16 + fr;
      int u = kc*4 + fq;
      const float* src = (const float*)(xa + p*256 + ((u ^ (p&7))*32));
      float4 lo = *(const float4*)src;
      float4 hi = *(const float4*)(src+4);
      bf16x8 a;
      a[0]=(short)f2bf(lo.x); a[1]=(short)f2bf(lo.y); a[2]=(short)f2bf(lo.z); a[3]=(short)f2bf(lo.w);
      a[4]=(short)f2bf(hi.x); a[5]=(short)f2bf(hi.y); a[6]=(short)f2bf(hi.z); a[7]=(short)f2bf(hi.w);
      af[mi] = a;
    }
    #pragma unroll
    for(int nf = 0; nf < 4; ++nf){
      int co = wc*64 + nf*16 + fr;
      int slot = (kc*4 + fq) ^ (co&7);
      bfr[nf] = *(const bf16x8*)(wb + co*128 + slot*16);
    }
    #pragma unroll
    for(int mi = 0; mi < 4; ++mi)
      #pragma unroll
      for(int nf = 0; nf < 4; ++nf)
        acc[mi][nf] = __builtin_amdgcn_mfma_f32_16x16x32_bf16(af[mi], bfr[nf], acc[mi][nf], 0,0,0);
  }
  __syncthreads();
  {
    const float rs = 0.9999950000374997f;
    float kb[4], ks[4], kbe[4];
    #pragma unroll
    for(int nf = 0; nf < 4; ++nf){
      int co = wc*64 + nf*16 + fr;
      kb[nf] = fe_b[co]; ks[nf] = fe_g[co]*rs; kbe[nf] = fe_beta[co];
    }
    #pragma unroll
    for(int mi = 0; mi < 4; ++mi)
      #pragma unroll
      for(int j = 0; j < 4; ++j){
        int px = wr*64 + mi*16 + fq*4 + j;
        float cf = conf[(size_t)n*HWPIX + hw0 + px];
        #pragma unroll
        for(int nf = 0; nf < 4; ++nf){
          float v = (acc[mi][nf][j] + kb[nf])*ks[nf] + kbe[nf];
          v = fmaxf(v, 0.f)*cf;
          int co = wc*64 + nf*16 + fr;
          *(unsigned short*)(xa + px*256 + ((co*2) ^ (((px>>2)&7)<<4))) = f2bf(v);
        }
      }
  }
  __syncthreads();
  {
    int p = tid>>1, half = tid&1;
    int r = rg*4 + (p>>5), c = p&31;
    unsigned short* dst = xe_pad + ((size_t)n*PPIX + (r+1)*PW2 + (c+1))*128 + half*64;
    #pragma unroll
    for(int s = 0; s < 8; ++s){
      int slot = half*8 + s;
      uint4 v = *(uint4*)(xa + p*256 + ((slot*16) ^ (((p>>2)&7)<<4)));
      *(uint4*)(dst + s*8) = v;
    }
  }
}

// ---------------- 3x3 conv: persistent per-image block, 18-row LDS ring -----
// 512 thr / 8 waves = 2M x 4N; wave tile 128px x 32co. A staged by
// global_load_lds (pre-swizzled source, linear LDS dest), prefetch of tile t+1
// issued before compute of tile t (latency hidden under ~10k cyc of compute).
// Dead ring rows double as epilogue scratch. W reg-direct from L2.
__launch_bounds__(512, 2)
__global__ void k_conv3(const unsigned short* __restrict__ inp,   // padded NHWC bf16
                        const unsigned short* __restrict__ Wb,    // [9][4][128][4][8]
                        const float* __restrict__ bnb, const float* __restrict__ bng,
                        const float* __restrict__ bnbe,
                        unsigned short* __restrict__ outp,
                        float* __restrict__ xnode_acc, int mode){  // 0: padded out, 1: flat out + xnode
  extern __shared__ char lds[];
  int tid = threadIdx.x;
  int n = blockIdx.x;
  const char* img = (const char*)inp + (size_t)n*PPIX*256;

  int wid = tid>>6, lane = tid&63;
  int wr = wid>>2, wc = wid&3, fr = lane&15, fq = lane>>4;  // wr 0..1, wc 0..3
  // pairs (wid, wid+4) share wc -> identical W stream (L1 reuse opportunity)
  const char* wlane = (const char*)Wb + (size_t)(wc*32 + fr)*64 + fq*16;

  // prologue: stage rows 0..9
  stage_rows(lds, img, 0, 5440, tid);
  __syncthreads();

  float xs = 0.f;
  const float rs = 0.9999950000374997f;
  float kb[2], ks[2], kbe[2];
  #pragma unroll
  for(int nf = 0; nf < 2; ++nf){
    int co = wc*32 + nf*16 + fr;
    kb[nf] = bnb[co]; ks[nf] = bng[co]*rs; kbe[nf] = bnbe[co];
  }

  #pragma unroll 1
  for(int t = 0; t < 4; ++t){
    int rbase = 8*t;
    // prefetch next tile's 8 rows (slots disjoint from current window & scratch)
    if(t < 3) stage_rows(lds, img, 8*t+10, 4352, tid);

    bf16x8 Wf[2][8];
    #pragma unroll
    for(int kc = 0; kc < 4; ++kc)
      #pragma unroll
      for(int nf = 0; nf < 2; ++nf)
        Wf[0][kc*2+nf] = *(const bf16x8*)(wlane + kc*8192 + nf*1024);

    f32x4 acc[8][2];
    #pragma unroll
    for(int a = 0; a < 8; ++a){ acc[a][0] = (f32x4){0.f,0.f,0.f,0.f};
                                acc[a][1] = (f32x4){0.f,0.f,0.f,0.f}; }

    #pragma unroll
    for(int tap = 0; tap < 9; ++tap){
      if(tap < 8){
        #pragma unroll
        for(int kc = 0; kc < 4; ++kc)
          #pragma unroll
          for(int nf = 0; nf < 2; ++nf)
            Wf[(tap+1)&1][kc*2+nf] =
              *(const bf16x8*)(wlane + (size_t)(tap+1)*32768 + kc*8192 + nf*1024);
      }
      int dy = tap/3 - 1, dx = tap - (tap/3)*3 - 1;
      #pragma unroll
      for(int kc = 0; kc < 4; ++kc){
        bf16x8 af[8];
        #pragma unroll
        for(int mi = 0; mi < 8; ++mi){
          int px = wr*128 + mi*16 + fr;
          int prow = rbase + 1 + (px>>5) + dy;
          int pcol = (px&31) + 1 + dx;
          int slot = prow - (prow >= RING ? RING : 0);
          af[mi] = *(const bf16x8*)(lds + slot*ROWB + pcol*256 +
                                    (((kc*4+fq) ^ ((prow+pcol)&7))<<4));
        }
        #pragma unroll
        for(int mi = 0; mi < 8; ++mi)
          #pragma unroll
          for(int nf = 0; nf < 2; ++nf)
            acc[mi][nf] = __builtin_amdgcn_mfma_f32_16x16x32_bf16(
                af[mi], Wf[tap&1][kc*2+nf], acc[mi][nf], 0,0,0);
      }
    }
    __syncthreads();   // window reads done; dead rows become scratch

    // epilogue: BN + relu -> dead-row LDS scratch
    #pragma unroll
    for(int mi = 0; mi < 8; ++mi)
      #pragma unroll
      for(int j = 0; j < 4; ++j){
        int px = wr*128 + mi*16 + fq*4 + j;      // 0..255
        int d = rbase + (px>>5); d -= (d >= RING ? RING : 0);
        #pragma unroll
        for(int nf = 0; nf < 2; ++nf){
          float v = (acc[mi][nf][j] + kb[nf])*ks[nf] + kbe[nf];
          v = fmaxf(v, 0.f);
          int co = wc*32 + nf*16 + fr;
          *(unsigned short*)(lds + (size_t)d*ROWB + (px&31)*256 +
                             ((co*2) ^ (((px>>2)&7)<<4))) = f2bf(v);
        }
      }
    __syncthreads();

    // coalesced store (+ xnode partial sums for mode 1)
    {
      int p = tid>>1, half = tid&1;               // p 0..255
      int d = rbase + (p>>5); d -= (d >= RING ? RING : 0);
      char* sb = lds + (size_t)d*ROWB + (p&31)*256;
      unsigned short* dst;
      if(mode == 0) dst = outp + ((size_t)n*PPIX + (t*8 + (p>>5) + 1)*PW2 + (p&31) + 1)*128 + half*64;
      else          dst = outp + ((size_t)n*HWPIX + t*256 + p)*128 + half*64;
      #pragma unroll
      for(int s = 0; s < 8; ++s){
        int slot = half*8 + s;
        uint4 v = *(uint4*)(sb + ((slot*16) ^ (((p>>2)&7)<<4)));
        *(uint4*)(dst + s*8) = v;
      }
    }
    if(mode == 1){
      int co = tid & 127, g = tid>>7;              // g 0..3, 64 px each
      #pragma unroll 8
      for(int i = 0; i < 64; ++i){
        int px = g*64 + i;
        int d = rbase + (px>>5); d -= (d >= RING ? RING : 0);
        xs += bf2f(*(unsigned short*)(lds + (size_t)d*ROWB + (px&31)*256 +
                                      ((co*2) ^ (((px>>2)&7)<<4))));
      }
    }
    __syncthreads();   // scratch consumed before next prefetch overwrites slots
  }
  if(mode == 1) atomicAdd(&xnode_acc[n*HIDC + (tid&127)], xs);
}

// ---------------- GAT linear: h = x@lin, plus per-head attn dots ------------
__global__ void k_gat_lin(const float* __restrict__ xin, float scale,
                          const float* __restrict__ lin,
                          const float* __restrict__ as_, const float* __restrict__ ad_,
                          float* __restrict__ h, float* __restrict__ a_s, float* __restrict__ a_d){
  __shared__ float xs[128];
  __shared__ float rs0[4], rs1[4], rd0[4], rd1[4];
  int n = blockIdx.x, t = threadIdx.x;
  if(t < 128) xs[t] = xin[n*128 + t]*scale;
  __syncthreads();
  float o0 = 0.f, o1 = 0.f;
  for(int k = 0; k < 128; ++k){
    float xv = xs[k];
    o0 += xv*lin[k*512 + t];
    o1 += xv*lin[k*512 + t + 256];
  }
  h[(size_t)n*512 + t] = o0;
  h[(size_t)n*512 + t + 256] = o1;
  float s0 = o0*as_[t], s1 = o1*as_[t+256];
  float d0 = o0*ad_[t], d1 = o1*ad_[t+256];
  #pragma unroll
  for(int o = 32; o; o >>= 1){
    s0 += __shfl_down(s0, o); s1 += __shfl_down(s1, o);
    d0 += __shfl_down(d0, o); d1 += __shfl_down(d1, o);
  }
  int w = t>>6;
  if((t&63) == 0){ rs0[w]=s0; rs1[w]=s1; rd0[w]=d0; rd1[w]=d1; }
  __syncthreads();
  if(t < 4){
    if(t < 2){
      a_s[n*4+t] = rs0[2*t] + rs0[2*t+1];
      a_d[n*4+t] = rd0[2*t] + rd0[2*t+1];
    } else {
      a_s[n*4+t] = rs1[2*(t-2)] + rs1[2*(t-2)+1];
      a_d[n*4+t] = rd1[2*(t-2)] + rd1[2*(t-2)+1];
    }
  }
}

// ---------------- GAT aggregate: per-dst softmax + weighted sum -------------
__global__ void k_gat_aggr(const int* __restrict__ offs, const int* __restrict__ csr_src,
                           const float* __restrict__ a_s, const float* __restrict__ a_d,
                           const float* __restrict__ h, const float* __restrict__ bias,
                           float* __restrict__ y){
  __shared__ int ssrc[2048];
  __shared__ float sex[4][2048];
  __shared__ float out4[512];
  __shared__ float adn[4], smax[4], sden[4];
  __shared__ float wred[4][4];
  int n = blockIdx.x, t = threadIdx.x;
  int base = offs[n], deg = offs[n+1] - base;
  if(t < 4) adn[t] = a_d[n*4 + t];
  __syncthreads();
  bool cached = (deg <= 2048);
  float lm0=-1e30f, lm1=-1e30f, lm2=-1e30f, lm3=-1e30f;
  for(int e = t; e < deg; e += 256){
    int s = csr_src[base + e];
    float v0 = a_s[s*4+0] + adn[0]; v0 = v0 > 0.f ? v0 : 0.2f*v0;
    float v1 = a_s[s*4+1] + adn[1]; v1 = v1 > 0.f ? v1 : 0.2f*v1;
    float v2 = a_s[s*4+2] + adn[2]; v2 = v2 > 0.f ? v2 : 0.2f*v2;
    float v3 = a_s[s*4+3] + adn[3]; v3 = v3 > 0.f ? v3 : 0.2f*v3;
    if(cached){ ssrc[e]=s; sex[0][e]=v0; sex[1][e]=v1; sex[2][e]=v2; sex[3][e]=v3; }
    lm0 = fmaxf(lm0, v0); lm1 = fmaxf(lm1, v1); lm2 = fmaxf(lm2, v2); lm3 = fmaxf(lm3, v3);
  }
  #pragma unroll
  for(int o = 32; o; o >>= 1){
    lm0 = fmaxf(lm0, __shfl_down(lm0, o)); lm1 = fmaxf(lm1, __shfl_down(lm1, o));
    lm2 = fmaxf(lm2, __shfl_down(lm2, o)); lm3 = fmaxf(lm3, __shfl_down(lm3, o));
  }
  int w = t>>6;
  if((t&63) == 0){ wred[w][0]=lm0; wred[w][1]=lm1; wred[w][2]=lm2; wred[w][3]=lm3; }
  __syncthreads();
  if(t < 4) smax[t] = fmaxf(fmaxf(wred[0][t], wred[1][t]), fmaxf(wred[2][t], wred[3][t]));
  __syncthreads();
  float m0 = smax[0], m1 = smax[1], m2 = smax[2], m3 = smax[3];
  float ls0=0.f, ls1=0.f, ls2=0.f, ls3=0.f;
  for(int e = t; e < deg; e += 256){
    float e0, e1, e2, e3;
    if(cached){ e0 = sex[0][e]; e1 = sex[1][e]; e2 = sex[2][e]; e3 = sex[3][e]; }
    else {
      int s = csr_src[base + e];
      e0 = a_s[s*4+0] + adn[0]; e0 = e0 > 0.f ? e0 : 0.2f*e0;
      e1 = a_s[s*4+1] + adn[1]; e1 = e1 > 0.f ? e1 : 0.2f*e1;
      e2 = a_s[s*4+2] + adn[2]; e2 = e2 > 0.f ? e2 : 0.2f*e2;
      e3 = a_s[s*4+3] + adn[3]; e3 = e3 > 0.f ? e3 : 0.2f*e3;
    }
    e0 = __expf(e0-m0); e1 = __expf(e1-m1); e2 = __expf(e2-m2); e3 = __expf(e3-m3);
    if(cached){ sex[0][e]=e0; sex[1][e]=e1; sex[2][e]=e2; sex[3][e]=e3; }
    ls0 += e0; ls1 += e1; ls2 += e2; ls3 += e3;
  }
  #pragma unroll
  for(int o = 32; o; o >>= 1){
    ls0 += __shfl_down(ls0, o); ls1 += __shfl_down(ls1, o);
    ls2 += __shfl_down(ls2, o); ls3 += __shfl_down(ls3, o);
  }
  __syncthreads();   // wred(max) fully consumed
  if((t&63) == 0){ wred[w][0]=ls0; wred[w][1]=ls1; wred[w][2]=ls2; wred[w][3]=ls3; }
  __syncthreads();
  if(t < 4) sden[t] = wred[0][t] + wred[1][t] + wred[2][t] + wred[3][t] + 1e-16f;
  __syncthreads();
  #pragma unroll
  for(int oo = 0; oo < 2; ++oo){
    int o = t + oo*256;
    int hd = o>>7, d = o&127;
    float mh = smax[hd];
    float accv = 0.f;
    for(int e = 0; e < deg; ++e){
      float ex; int s;
      if(cached){ ex = sex[hd][e]; s = ssrc[e]; }
      else {
        s = csr_src[base + e];
        float v = a_s[s*4+hd] + adn[hd]; v = v > 0.f ? v : 0.2f*v;
        ex = __expf(v - mh);
      }
      accv += ex * h[(size_t)s*512 + hd*128 + d];
    }
    out4[o] = accv / sden[hd];
  }
  __syncthreads();
  if(t < 128){
    float v = (out4[t] + out4[128+t] + out4[256+t] + out4[384+t])*0.25f + bias[t];
    y[n*128 + t] = fmaxf(v, 0.f);
  }
}

// ---------------- per-node bias for final conv: nb = op_w @ xg2 + op_b ------
__global__ void k_nodebias(const float* __restrict__ xg2, const float* __restrict__ op_w,
                           const float* __restrict__ op_b, float* __restrict__ nb){
  int g = blockIdx.x*256 + threadIdx.x;
  if(g < NIMG*64){
    int n = g>>6, co = g&63;
    float acc = op_b[co];
    for(int k = 0; k < 128; ++k) acc += op_w[co*128+k]*xg2[n*128+k];
    nb[g] = acc;
  }
}

// ---------------- final 1x1 conv: out = op_w@xp2 + nb, NCHW f32 -------------
__launch_bounds__(256, 2)
__global__ void k_outconv(const unsigned short* __restrict__ xp2,
                          const unsigned short* __restrict__ Wop,
                          const float* __restrict__ nb, float* __restrict__ out){
  __shared__ char lds[16384];
  int tid = threadIdx.x;
  int n = blockIdx.x>>3, rg = blockIdx.x&7;
  #pragma unroll
  for(int it = 0; it < 4; ++it){
    uint4 v = *(const uint4*)((const char*)Wop + it*4096 + tid*16);
    *(uint4*)(lds + it*4096 + tid*16) = v;
  }
  __syncthreads();
  int wid = tid>>6, lane = tid&63;
  int wr = wid>>1, wc = wid&1, fr = lane&15, fq = lane>>4;
  f32x4 acc[4][2];
  #pragma unroll
  for(int a = 0; a < 4; ++a){ acc[a][0] = (f32x4){0.f,0.f,0.f,0.f}; acc[a][1] = (f32x4){0.f,0.f,0.f,0.f}; }
  const unsigned short* abase = xp2 + ((size_t)n*HWPIX + rg*128)*128;
  #pragma unroll
  for(int kc = 0; kc < 4; ++kc){
    bf16x8 af[4], bfr[2];
    #pragma unroll
    for(int mi = 0; mi < 4; ++mi){
      int p = wr*64 + mi*16 + fr;
      af[mi] = *(const bf16x8*)(abase + p*128 + kc*32 + fq*8);
    }
    #pragma unroll
    for(int nf = 0; nf < 2; ++nf){
      int co = wc*32 + nf*16 + fr;
      int slot = (kc*4 + fq) ^ (co&7);
      bfr[nf] = *(const bf16x8*)(lds + co*256 + slot*16);
    }
    #pragma unroll
    for(int mi = 0; mi < 4; ++mi)
      #pragma unroll
      for(int nf = 0; nf < 2; ++nf)
        acc[mi][nf] = __builtin_amdgcn_mfma_f32_16x16x32_bf16(af[mi], bfr[nf], acc[mi][nf], 0,0,0);
  }
  #pragma unroll
  for(int mi = 0; mi < 4; ++mi)
    #pragma unroll
    for(int nf = 0; nf < 2; ++nf){
      int co = wc*32 + nf*16 + fr;
      int hw = rg*128 + wr*64 + mi*16 + fq*4;
      float nbv = nb[n*64 + co];
      float4 v = { acc[mi][nf][0]+nbv, acc[mi][nf][1]+nbv, acc[mi][nf][2]+nbv, acc[mi][nf][3]+nbv };
      *(float4*)(out + ((size_t)n*64 + co)*HWPIX + hw) = v;
    }
}

// ---------------- host launch ----------------------------------------------
extern "C" void kernel_launch(void* const* d_in, const int* in_sizes, int n_in,
                              void* d_out, int out_size, void* d_ws, size_t ws_size,
                              hipStream_t stream){
  const float* x       = (const float*)d_in[0];
  const int*   ei      = (const int*)d_in[1];
  const float* conf    = (const float*)d_in[2];
  const float* fe_w    = (const float*)d_in[3];
  const float* fe_b    = (const float*)d_in[4];
  const float* fe_g    = (const float*)d_in[5];
  const float* fe_beta = (const float*)d_in[6];
  const float* sp_w1   = (const float*)d_in[7];
  const float* sp_b1   = (const float*)d_in[8];
  const float* sp_g1   = (const float*)d_in[9];
  const float* sp_be1  = (const float*)d_in[10];
  const float* sp_w2   = (const float*)d_in[11];
  const float* sp_b2   = (const float*)d_in[12];
  const float* sp_g2   = (const float*)d_in[13];
  const float* sp_be2  = (const float*)d_in[14];
  const float* g1_lin  = (const float*)d_in[15];
  const float* g1_as   = (const float*)d_in[16];
  const float* g1_ad   = (const float*)d_in[17];
  const float* g1_b    = (const float*)d_in[18];
  const float* g2_lin  = (const float*)d_in[19];
  const float* g2_as   = (const float*)d_in[20];
  const float* g2_ad   = (const float*)d_in[21];
  const float* g2_b    = (const float*)d_in[22];
  const float* op_w    = (const float*)d_in[23];
  const float* op_b    = (const float*)d_in[24];
  float* out = (float*)d_out;

  char* ws = (char*)d_ws;
  size_t off = 0;
  auto alloc = [&](size_t bytes)->char*{
    char* p = ws + off; off += (bytes + 255) & ~(size_t)255; return p;
  };
  unsigned short* bigA  = (unsigned short*)alloc((size_t)NIMG*PPIX*128*2); // xe_pad, later xp2
  unsigned short* xp1   = (unsigned short*)alloc((size_t)NIMG*PPIX*128*2);
  unsigned short* Wb1   = (unsigned short*)alloc(147456*2);
  unsigned short* Wb2   = (unsigned short*)alloc(147456*2);
  unsigned short* Wfe   = (unsigned short*)alloc(8192*2);
  unsigned short* Wop   = (unsigned short*)alloc(8192*2);
  float* xnode_acc = (float*)alloc(NIMG*HIDC*4);
  float* h     = (float*)alloc((size_t)NIMG*512*4);
  float* a_s   = (float*)alloc(NIMG*4*4);
  float* a_d   = (float*)alloc(NIMG*4*4);
  float* xg1   = (float*)alloc(NIMG*HIDC*4);
  float* xg2   = (float*)alloc(NIMG*HIDC*4);
  int* cnt     = (int*)alloc(NIMG*4);
  int* pos     = (int*)alloc(NIMG*4);
  int* offs    = (int*)alloc((NIMG+1)*4);
  int* csr_src = (int*)alloc((NEDGE+NIMG)*4);
  float* nb    = (float*)alloc(NIMG*64*4);
  if(off > ws_size) return;   // workspace too small — bail cleanly
  unsigned short* xp2 = bigA; // reuse region A after conv1 consumed xe

  // 156672 B dynamic LDS for k_conv3 (18-row ring); 1 block/CU, 8 waves.
  hipFuncSetAttribute((const void*)k_conv3,
                      hipFuncAttributeMaxDynamicSharedMemorySize, 156672);

  k_init<<<1024, 256, 0, stream>>>(bigA, xp1, xnode_acc, cnt, pos);
  k_wconv<<<576, 256, 0, stream>>>(sp_w1, sp_w2, fe_w, op_w, Wb1, Wb2, Wfe, Wop);
  k_csr_count<<<(NEDGE+255)/256, 256, 0, stream>>>(ei, cnt);
  k_csr_scan<<<1, 512, 0, stream>>>(cnt, offs);
  k_csr_fill<<<(NEDGE+NIMG+255)/256, 256, 0, stream>>>(ei, offs, pos, csr_src);
  k_encode<<<4096, 256, 0, stream>>>(x, conf, Wfe, fe_b, fe_g, fe_beta, bigA);
  k_conv3<<<512, 512, 156672, stream>>>(bigA, Wb1, sp_b1, sp_g1, sp_be1, xp1, xnode_acc, 0);
  k_conv3<<<512, 512, 156672, stream>>>(xp1, Wb2, sp_b2, sp_g2, sp_be2, xp2, xnode_acc, 1);
  k_gat_lin<<<512, 256, 0, stream>>>(xnode_acc, 1.f/1024.f, g1_lin, g1_as, g1_ad, h, a_s, a_d);
  k_gat_aggr<<<512, 256, 0, stream>>>(offs, csr_src, a_s, a_d, h, g1_b, xg1);
  k_gat_lin<<<512, 256, 0, stream>>>(xg1, 1.f, g2_lin, g2_as, g2_ad, h, a_s, a_d);
  k_gat_aggr<<<512, 256, 0, stream>>>(offs, csr_src, a_s, a_d, h, g2_b, xg2);
  k_nodebias<<<(NIMG*64+255)/256, 256, 0, stream>>>(xg2, op_w, op_b, nb);
  k_outconv<<<4096, 256, 0, stream>>>(xp2, Wop, nb, out);
}

// Round 7
// 597.600 us; speedup vs baseline: 2.9996x; 2.9996x over previous
//
#include <hip/hip_runtime.h>
#include <stdint.h>

#define NIMG 512
#define CINCH 64
#define HIDC 128
#define NEDGE 16384
#define HWPIX 1024
#define PW2 34
#define PPIX 1156   // 34*34

typedef __attribute__((ext_vector_type(8))) short bf16x8;
typedef __attribute__((ext_vector_type(4))) float f32x4;
typedef __attribute__((ext_vector_type(16))) float f32x16;

static __device__ __forceinline__ unsigned short f2bf(float f){
  unsigned u = __builtin_bit_cast(unsigned, f);
  u += 0x7FFFu + ((u>>16)&1u);
  return (unsigned short)(u>>16);
}
static __device__ __forceinline__ float bf2f(unsigned short s){
  unsigned u = ((unsigned)s)<<16;
  return __builtin_bit_cast(float, u);
}

// async 16B global->LDS, both sides linear (swizzle baked into global layout)
static __device__ __forceinline__ void gload16(const char* src, char* dst){
  __builtin_amdgcn_global_load_lds(
      (const __attribute__((address_space(1))) unsigned int*)src,
      (__attribute__((address_space(3))) unsigned int*)dst, 16, 0, 0);
}

// ---------------- init: zero pad borders + accumulators + csr counters ------
__global__ void k_init(unsigned short* xe_pad, unsigned short* xp1_pad,
                       float* xnode_acc, int* cnt, int* pos){
  int idx = blockIdx.x*256 + threadIdx.x;
  int total_b = NIMG*132*16;
  for(int i = idx; i < total_b; i += gridDim.x*256){
    int img = i / (132*16);
    int rem = i - img*(132*16);
    int bp = rem >> 4;
    int slot = rem & 15;
    int r, c;
    if(bp < 34){ r = 0; c = bp; }
    else if(bp < 68){ r = 33; c = bp-34; }
    else if(bp < 100){ r = bp-68+1; c = 0; }
    else { r = bp-100+1; c = 33; }
    size_t off = ((size_t)img*PPIX + r*PW2 + c)*128 + slot*8;
    uint4 z = {0,0,0,0};
    *(uint4*)(xe_pad + off) = z;
    *(uint4*)(xp1_pad + off) = z;
  }
  for(int i = idx; i < NIMG*HIDC; i += gridDim.x*256) xnode_acc[i] = 0.f;
  for(int i = idx; i < NIMG; i += gridDim.x*256){ cnt[i] = 0; pos[i] = 0; }
}

// ---------------- weight conversion ------------------------------------------
// conv3 W image: [tap][co][cc 0..15][8] bf16, chunk cc holds cin-group (cc^(co&7)).
// Staged linearly into LDS; conv3 reads chunk (g ^ (co&7)) to get cin-group g.
__global__ void k_wconv(const float* __restrict__ sp_w1, const float* __restrict__ sp_w2,
                        const float* __restrict__ fe_w, const float* __restrict__ op_w,
                        unsigned short* Wb1, unsigned short* Wb2,
                        unsigned short* Wfe, unsigned short* Wop){
  int idx = blockIdx.x*256 + threadIdx.x;
  for(int i = idx; i < 147456; i += gridDim.x*256){
    int j = i & 7, cc = (i>>3)&15, co = (i>>7)&127, tap = i>>14;
    int cin = ((cc ^ (co&7))<<3) + j;
    Wb1[i] = f2bf(sp_w1[(co*128+cin)*9 + tap]);
    Wb2[i] = f2bf(sp_w2[(co*128+cin)*9 + tap]);
  }
  for(int i = idx; i < 8192; i += gridDim.x*256){
    int j = i & 7, s = (i>>3)&7, co = i>>6;
    int ci = ((s ^ (co&7))<<3) + j;
    Wfe[i] = f2bf(fe_w[co*64+ci]);
  }
  for(int i = idx; i < 8192; i += gridDim.x*256){
    int j = i & 7, s = (i>>3)&15, co = i>>7;   // co 0..63
    int cin = ((s ^ (co&7))<<3) + j;
    Wop[i] = f2bf(op_w[co*128+cin]);
  }
}

// ---------------- CSR build ------------------------------------------------
__global__ void k_csr_count(const int* __restrict__ ei, int* cnt){
  int e = blockIdx.x*256 + threadIdx.x;
  if(e < NEDGE) atomicAdd(&cnt[ei[NEDGE+e]], 1);
}
__global__ void k_csr_scan(const int* __restrict__ cnt, int* offs){
  __shared__ int sc[512];
  int t = threadIdx.x;
  sc[t] = cnt[t] + 1;   // +1 for self loop
  __syncthreads();
  for(int o = 1; o < 512; o <<= 1){
    int add = (t >= o) ? sc[t-o] : 0;
    __syncthreads();
    sc[t] += add;
    __syncthreads();
  }
  if(t == 0) offs[0] = 0;
  offs[t+1] = sc[t];
}
__global__ void k_csr_fill(const int* __restrict__ ei, const int* __restrict__ offs,
                           int* pos, int* csr_src){
  int e = blockIdx.x*256 + threadIdx.x;
  if(e < NEDGE + NIMG){
    int s, d;
    if(e < NEDGE){ s = ei[e]; d = ei[NEDGE+e]; }
    else { s = e - NEDGE; d = s; }
    int slot = offs[d] + atomicAdd(&pos[d], 1);
    csr_src[slot] = s;
  }
}

// ---------------- encode: 1x1 conv + BN + relu + conf, padded NHWC (baked) --
__launch_bounds__(256, 2)
__global__ void k_encode(const float* __restrict__ x, const float* __restrict__ conf,
                         const unsigned short* __restrict__ Wfe,
                         const float* __restrict__ fe_b, const float* __restrict__ fe_g,
                         const float* __restrict__ fe_beta,
                         unsigned short* __restrict__ xe_pad){
  __shared__ char lds[49152];          // xa 32KB (f32 swizzled) + wb 16KB
  char* xa = lds; char* wb = lds + 32768;
  int tid = threadIdx.x;
  int n = blockIdx.x >> 3, rg = blockIdx.x & 7;
  int hw0 = rg*128;
  {
    int q = tid >> 3, c0 = tid & 7;
    const float* xb = x + (size_t)n*CINCH*HWPIX + hw0;
    #pragma unroll
    for(int cc = 0; cc < 8; ++cc){
      int c = cc*8 + c0;
      float4 v = *(const float4*)(xb + (size_t)c*HWPIX + q*4);
      float vv[4] = {v.x, v.y, v.z, v.w};
      #pragma unroll
      for(int i = 0; i < 4; ++i){
        int p = q*4 + i;
        *(float*)(xa + p*256 + ((cc ^ (p&7))*32) + c0*4) = vv[i];
      }
    }
    #pragma unroll
    for(int it = 0; it < 4; ++it){
      uint4 w = *(const uint4*)((const char*)Wfe + it*4096 + tid*16);
      *(uint4*)(wb + it*4096 + tid*16) = w;
    }
  }
  __syncthreads();
  int wid = tid>>6, lane = tid&63;
  int wr = wid>>1, wc = wid&1, fr = lane&15, fq = lane>>4;
  f32x4 acc[4][4];
  #pragma unroll
  for(int a = 0; a < 4; ++a)
    #pragma unroll
    for(int b = 0; b < 4; ++b) acc[a][b] = (f32x4){0.f,0.f,0.f,0.f};
  #pragma unroll
  for(int kc = 0; kc < 2; ++kc){
    bf16x8 af[4], bfr[4];
    #pragma unroll
    for(int mi = 0; mi < 4; ++mi){
      int p = wr*64 + mi*16 + fr;
      int u = kc*4 + fq;
      const float* src = (const float*)(xa + p*256 + ((u ^ (p&7))*32));
      float4 lo = *(const float4*)src;
      float4 hi = *(const float4*)(src+4);
      bf16x8 a;
      a[0]=(short)f2bf(lo.x); a[1]=(short)f2bf(lo.y); a[2]=(short)f2bf(lo.z); a[3]=(short)f2bf(lo.w);
      a[4]=(short)f2bf(hi.x); a[5]=(short)f2bf(hi.y); a[6]=(short)f2bf(hi.z); a[7]=(short)f2bf(hi.w);
      af[mi] = a;
    }
    #pragma unroll
    for(int nf = 0; nf < 4; ++nf){
      int co = wc*64 + nf*16 + fr;
      int slot = (kc*4 + fq) ^ (co&7);
      bfr[nf] = *(const bf16x8*)(wb + co*128 + slot*16);
    }
    #pragma unroll
    for(int mi = 0; mi < 4; ++mi)
      #pragma unroll
      for(int nf = 0; nf < 4; ++nf)
        acc[mi][nf] = __builtin_amdgcn_mfma_f32_16x16x32_bf16(af[mi], bfr[nf], acc[mi][nf], 0,0,0);
  }
  __syncthreads();
  {
    const float rs = 0.9999950000374997f;
    float kb[4], ks[4], kbe[4];
    #pragma unroll
    for(int nf = 0; nf < 4; ++nf){
      int co = wc*64 + nf*16 + fr;
      kb[nf] = fe_b[co]; ks[nf] = fe_g[co]*rs; kbe[nf] = fe_beta[co];
    }
    #pragma unroll
    for(int mi = 0; mi < 4; ++mi)
      #pragma unroll
      for(int j = 0; j < 4; ++j){
        int px = wr*64 + mi*16 + fq*4 + j;
        float cf = conf[(size_t)n*HWPIX + hw0 + px];
        #pragma unroll
        for(int nf = 0; nf < 4; ++nf){
          float v = (acc[mi][nf][j] + kb[nf])*ks[nf] + kbe[nf];
          v = fmaxf(v, 0.f)*cf;
          int co = wc*64 + nf*16 + fr;
          *(unsigned short*)(xa + px*256 + ((co*2) ^ (((px>>2)&7)<<4))) = f2bf(v);
        }
      }
  }
  __syncthreads();
  {
    int p = tid>>1, half = tid&1;
    int r = rg*4 + (p>>5), c = p&31;
    int key = (2*(p>>5) + (p&31) + 3) & 7;   // (2(r+1)+(c+1))&7, 8rg==0 mod 8
    unsigned short* dst = xe_pad + ((size_t)n*PPIX + (r+1)*PW2 + (c+1))*128;
    #pragma unroll
    for(int s = 0; s < 8; ++s){
      int ls = half*8 + s;
      uint4 v = *(uint4*)(xa + p*256 + ((ls*16) ^ (((p>>2)&7)<<4)));
      *(uint4*)(dst + (ls ^ key)*8) = v;
    }
  }
}

// ---------------- 3x3 conv: 8 waves, 32x32x16 MFMA, gload_lds staging -------
// Block: 8 rows x 32 cols x 128co. Wave tile 64px(2 rows) x 64co (2x2 frags).
// LDS: A tile 340px x 256B = 87040 (full K, baked chunk-XOR, staged linearly
// once) + W tap double-buffer 2x32KB (baked XOR, staged linearly per tap).
// One barrier per tap; stage(t+1) issued at loop top, drains under MFMA.
__launch_bounds__(512, 2)
__global__ void k_conv3(const unsigned short* __restrict__ inp,   // padded, baked
                        const unsigned short* __restrict__ Wb,    // [9][128][16][8] baked
                        const float* __restrict__ bnb, const float* __restrict__ bng,
                        const float* __restrict__ bnbe,
                        unsigned short* __restrict__ outp,
                        float* __restrict__ xnode_acc, int mode){
  extern __shared__ char lds[];
  char* Ab = lds;                 // 87040
  char* Wd = lds + 87040;         // 2 x 32768
  int tid = threadIdx.x;
  int n = blockIdx.x>>2, rg = blockIdx.x&3;

  const char* img  = (const char*)inp + ((size_t)n*PPIX + (size_t)rg*8*PW2)*256;
  const char* wsrc = (const char*)Wb;

  // prologue: stage W tap0 + A tile, all linear gload_lds
  #pragma unroll
  for(int it = 0; it < 4; ++it)
    gload16(wsrc + it*8192 + tid*16, Wd + it*8192 + tid*16);
  #pragma unroll
  for(int it = 0; it < 11; ++it){
    int j = tid + it*512;
    if(it < 10 || j < 5440) gload16(img + (size_t)j*16, Ab + (size_t)j*16);
  }

  int wid = tid>>6, lane = tid&63;
  int wr = wid>>1, wc = wid&1;                 // wr 0..3 (row pair), wc 0..1 (co half)
  int col = lane&31, hi = lane>>5;
  int cobase0 = (wc*64 + col)*256;             // nf=0 row base in W image
  int cokeyx = col&7;                          // co&7 (wc*64,nf*32 are 0 mod 8)

  f32x16 acc[2][2];
  #pragma unroll
  for(int a = 0; a < 2; ++a)
    #pragma unroll
    for(int b = 0; b < 2; ++b)
      #pragma unroll
      for(int r = 0; r < 16; ++r) acc[a][b][r] = 0.f;

  __syncthreads();

  for(int tap = 0; tap < 9; ++tap){
    // stage next tap's W into the other buffer (reads of it finished last tap)
    if(tap < 8){
      const char* ws = wsrc + (size_t)(tap+1)*32768;
      char* wdst = Wd + ((tap+1)&1)*32768;
      #pragma unroll
      for(int it = 0; it < 4; ++it)
        gload16(ws + it*8192 + tid*16, wdst + it*8192 + tid*16);
    }
    const char* cur = Wd + (tap&1)*32768;
    int dy = tap/3 - 1, dx = tap - (tap/3)*3 - 1;
    int pcol = col + 1 + dx;
    int prow0 = wr*2 + 1 + dy;                  // mi=0 sample row (0..9)
    int abase0 = prow0*8704 + pcol*256;         // 34*256 = 8704
    int key0 = (2*prow0 + pcol) & 7;
    int key1 = (key0 + 2) & 7;                  // prow+1 -> key+2 mod 8

    __builtin_amdgcn_s_setprio(1);
    #pragma unroll
    for(int kc = 0; kc < 8; ++kc){
      int g = kc*2 + hi;
      bf16x8 af0 = *(const bf16x8*)(Ab + abase0 + ((g ^ key0)<<4));
      bf16x8 af1 = *(const bf16x8*)(Ab + abase0 + 8704 + ((g ^ key1)<<4));
      int wco = (g ^ cokeyx)<<4;
      bf16x8 wf0 = *(const bf16x8*)(cur + cobase0 + wco);
      bf16x8 wf1 = *(const bf16x8*)(cur + cobase0 + 8192 + wco);  // nf=1: +32co*256
      acc[0][0] = __builtin_amdgcn_mfma_f32_32x32x16_bf16(af0, wf0, acc[0][0], 0,0,0);
      acc[0][1] = __builtin_amdgcn_mfma_f32_32x32x16_bf16(af0, wf1, acc[0][1], 0,0,0);
      acc[1][0] = __builtin_amdgcn_mfma_f32_32x32x16_bf16(af1, wf0, acc[1][0], 0,0,0);
      acc[1][1] = __builtin_amdgcn_mfma_f32_32x32x16_bf16(af1, wf1, acc[1][1], 0,0,0);
    }
    __builtin_amdgcn_s_setprio(0);
    __syncthreads();   // all reads of cur done + next stage landed (vmcnt drain)
  }

  // epilogue: BN + relu -> LDS transpose scratch (reuse A region)
  char* eb = Ab;
  {
    const float rs = 0.9999950000374997f;
    float kb[2], ks[2], kbe[2];
    #pragma unroll
    for(int nf = 0; nf < 2; ++nf){
      int co = wc*64 + nf*32 + col;
      kb[nf] = bnb[co]; ks[nf] = bng[co]*rs; kbe[nf] = bnbe[co];
    }
    #pragma unroll
    for(int mi = 0; mi < 2; ++mi)
      #pragma unroll
      for(int reg = 0; reg < 16; ++reg){
        int pc = (reg&3) + 8*(reg>>2) + 4*hi;   // pixel col within row
        int px = (wr*2 + mi)*32 + pc;           // block-local 0..255
        #pragma unroll
        for(int nf = 0; nf < 2; ++nf){
          float v = (acc[mi][nf][reg] + kb[nf])*ks[nf] + kbe[nf];
          v = fmaxf(v, 0.f);
          int co = wc*64 + nf*32 + col;
          *(unsigned short*)(eb + px*256 + ((co*2) ^ (((px>>2)&7)<<4))) = f2bf(v);
        }
      }
  }
  __syncthreads();
  {
    int p = tid>>1, half = tid&1;               // p 0..255
    int r = rg*8 + (p>>5), c = p&31;
    unsigned short* dst;
    int key;
    if(mode == 0){
      key = (2*(p>>5) + (p&31) + 3) & 7;        // padded-layout key
      dst = outp + ((size_t)n*PPIX + (r+1)*PW2 + (c+1))*128;
    } else {
      key = p & 7;                               // flat-layout key (hw&7)
      dst = outp + ((size_t)n*HWPIX + rg*256 + p)*128;
    }
    #pragma unroll
    for(int s = 0; s < 8; ++s){
      int ls = half*8 + s;
      uint4 v = *(uint4*)(eb + p*256 + ((ls*16) ^ (((p>>2)&7)<<4)));
      *(uint4*)(dst + (ls ^ key)*8) = v;
    }
  }
  if(mode == 1){
    int co = tid & 127, g = tid>>7;              // g 0..3, 64 px each
    float sum = 0.f;
    #pragma unroll 8
    for(int i = 0; i < 64; ++i){
      int px = g*64 + i;
      sum += bf2f(*(unsigned short*)(eb + px*256 + ((co*2) ^ (((px>>2)&7)<<4))));
    }
    atomicAdd(&xnode_acc[n*HIDC + co], sum);
  }
}

// ---------------- GAT linear: h = x@lin, plus per-head attn dots ------------
__global__ void k_gat_lin(const float* __restrict__ xin, float scale,
                          const float* __restrict__ lin,
                          const float* __restrict__ as_, const float* __restrict__ ad_,
                          float* __restrict__ h, float* __restrict__ a_s, float* __restrict__ a_d){
  __shared__ float xs[128];
  __shared__ float rs0[4], rs1[4], rd0[4], rd1[4];
  int n = blockIdx.x, t = threadIdx.x;
  if(t < 128) xs[t] = xin[n*128 + t]*scale;
  __syncthreads();
  float o0 = 0.f, o1 = 0.f;
  for(int k = 0; k < 128; ++k){
    float xv = xs[k];
    o0 += xv*lin[k*512 + t];
    o1 += xv*lin[k*512 + t + 256];
  }
  h[(size_t)n*512 + t] = o0;
  h[(size_t)n*512 + t + 256] = o1;
  float s0 = o0*as_[t], s1 = o1*as_[t+256];
  float d0 = o0*ad_[t], d1 = o1*ad_[t+256];
  #pragma unroll
  for(int o = 32; o; o >>= 1){
    s0 += __shfl_down(s0, o); s1 += __shfl_down(s1, o);
    d0 += __shfl_down(d0, o); d1 += __shfl_down(d1, o);
  }
  int w = t>>6;
  if((t&63) == 0){ rs0[w]=s0; rs1[w]=s1; rd0[w]=d0; rd1[w]=d1; }
  __syncthreads();
  if(t < 4){
    if(t < 2){
      a_s[n*4+t] = rs0[2*t] + rs0[2*t+1];
      a_d[n*4+t] = rd0[2*t] + rd0[2*t+1];
    } else {
      a_s[n*4+t] = rs1[2*(t-2)] + rs1[2*(t-2)+1];
      a_d[n*4+t] = rd1[2*(t-2)] + rd1[2*(t-2)+1];
    }
  }
}

// ---------------- GAT aggregate: per-dst softmax + weighted sum -------------
__global__ void k_gat_aggr(const int* __restrict__ offs, const int* __restrict__ csr_src,
                           const float* __restrict__ a_s, const float* __restrict__ a_d,
                           const float* __restrict__ h, const float* __restrict__ bias,
                           float* __restrict__ y){
  __shared__ int ssrc[2048];
  __shared__ float sex[4][2048];
  __shared__ float out4[512];
  __shared__ float adn[4], smax[4], sden[4];
  __shared__ float wred[4][4];
  int n = blockIdx.x, t = threadIdx.x;
  int base = offs[n], deg = offs[n+1] - base;
  if(t < 4) adn[t] = a_d[n*4 + t];
  __syncthreads();
  bool cached = (deg <= 2048);
  float lm0=-1e30f, lm1=-1e30f, lm2=-1e30f, lm3=-1e30f;
  for(int e = t; e < deg; e += 256){
    int s = csr_src[base + e];
    float v0 = a_s[s*4+0] + adn[0]; v0 = v0 > 0.f ? v0 : 0.2f*v0;
    float v1 = a_s[s*4+1] + adn[1]; v1 = v1 > 0.f ? v1 : 0.2f*v1;
    float v2 = a_s[s*4+2] + adn[2]; v2 = v2 > 0.f ? v2 : 0.2f*v2;
    float v3 = a_s[s*4+3] + adn[3]; v3 = v3 > 0.f ? v3 : 0.2f*v3;
    if(cached){ ssrc[e]=s; sex[0][e]=v0; sex[1][e]=v1; sex[2][e]=v2; sex[3][e]=v3; }
    lm0 = fmaxf(lm0, v0); lm1 = fmaxf(lm1, v1); lm2 = fmaxf(lm2, v2); lm3 = fmaxf(lm3, v3);
  }
  #pragma unroll
  for(int o = 32; o; o >>= 1){
    lm0 = fmaxf(lm0, __shfl_down(lm0, o)); lm1 = fmaxf(lm1, __shfl_down(lm1, o));
    lm2 = fmaxf(lm2, __shfl_down(lm2, o)); lm3 = fmaxf(lm3, __shfl_down(lm3, o));
  }
  int w = t>>6;
  if((t&63) == 0){ wred[w][0]=lm0; wred[w][1]=lm1; wred[w][2]=lm2; wred[w][3]=lm3; }
  __syncthreads();
  if(t < 4) smax[t] = fmaxf(fmaxf(wred[0][t], wred[1][t]), fmaxf(wred[2][t], wred[3][t]));
  __syncthreads();
  float m0 = smax[0], m1 = smax[1], m2 = smax[2], m3 = smax[3];
  float ls0=0.f, ls1=0.f, ls2=0.f, ls3=0.f;
  for(int e = t; e < deg; e += 256){
    float e0, e1, e2, e3;
    if(cached){ e0 = sex[0][e]; e1 = sex[1][e]; e2 = sex[2][e]; e3 = sex[3][e]; }
    else {
      int s = csr_src[base + e];
      e0 = a_s[s*4+0] + adn[0]; e0 = e0 > 0.f ? e0 : 0.2f*e0;
      e1 = a_s[s*4+1] + adn[1]; e1 = e1 > 0.f ? e1 : 0.2f*e1;
      e2 = a_s[s*4+2] + adn[2]; e2 = e2 > 0.f ? e2 : 0.2f*e2;
      e3 = a_s[s*4+3] + adn[3]; e3 = e3 > 0.f ? e3 : 0.2f*e3;
    }
    e0 = __expf(e0-m0); e1 = __expf(e1-m1); e2 = __expf(e2-m2); e3 = __expf(e3-m3);
    if(cached){ sex[0][e]=e0; sex[1][e]=e1; sex[2][e]=e2; sex[3][e]=e3; }
    ls0 += e0; ls1 += e1; ls2 += e2; ls3 += e3;
  }
  #pragma unroll
  for(int o = 32; o; o >>= 1){
    ls0 += __shfl_down(ls0, o); ls1 += __shfl_down(ls1, o);
    ls2 += __shfl_down(ls2, o); ls3 += __shfl_down(ls3, o);
  }
  __syncthreads();   // wred(max) fully consumed
  if((t&63) == 0){ wred[w][0]=ls0; wred[w][1]=ls1; wred[w][2]=ls2; wred[w][3]=ls3; }
  __syncthreads();
  if(t < 4) sden[t] = wred[0][t] + wred[1][t] + wred[2][t] + wred[3][t] + 1e-16f;
  __syncthreads();
  #pragma unroll
  for(int oo = 0; oo < 2; ++oo){
    int o = t + oo*256;
    int hd = o>>7, d = o&127;
    float mh = smax[hd];
    float accv = 0.f;
    for(int e = 0; e < deg; ++e){
      float ex; int s;
      if(cached){ ex = sex[hd][e]; s = ssrc[e]; }
      else {
        s = csr_src[base + e];
        float v = a_s[s*4+hd] + adn[hd]; v = v > 0.f ? v : 0.2f*v;
        ex = __expf(v - mh);
      }
      accv += ex * h[(size_t)s*512 + hd*128 + d];
    }
    out4[o] = accv / sden[hd];
  }
  __syncthreads();
  if(t < 128){
    float v = (out4[t] + out4[128+t] + out4[256+t] + out4[384+t])*0.25f + bias[t];
    y[n*128 + t] = fmaxf(v, 0.f);
  }
}

// ---------------- per-node bias for final conv: nb = op_w @ xg2 + op_b ------
__global__ void k_nodebias(const float* __restrict__ xg2, const float* __restrict__ op_w,
                           const float* __restrict__ op_b, float* __restrict__ nb){
  int g = blockIdx.x*256 + threadIdx.x;
  if(g < NIMG*64){
    int n = g>>6, co = g&63;
    float acc = op_b[co];
    for(int k = 0; k < 128; ++k) acc += op_w[co*128+k]*xg2[n*128+k];
    nb[g] = acc;
  }
}

// ---------------- final 1x1 conv: out = op_w@xp2 + nb, NCHW f32 -------------
__launch_bounds__(256, 2)
__global__ void k_outconv(const unsigned short* __restrict__ xp2,  // flat, baked key=hw&7
                          const unsigned short* __restrict__ Wop,
                          const float* __restrict__ nb, float* __restrict__ out){
  __shared__ char lds[16384];
  int tid = threadIdx.x;
  int n = blockIdx.x>>3, rg = blockIdx.x&7;
  #pragma unroll
  for(int it = 0; it < 4; ++it){
    uint4 v = *(const uint4*)((const char*)Wop + it*4096 + tid*16);
    *(uint4*)(lds + it*4096 + tid*16) = v;
  }
  __syncthreads();
  int wid = tid>>6, lane = tid&63;
  int wr = wid>>1, wc = wid&1, fr = lane&15, fq = lane>>4;
  f32x4 acc[4][2];
  #pragma unroll
  for(int a = 0; a < 4; ++a){ acc[a][0] = (f32x4){0.f,0.f,0.f,0.f}; acc[a][1] = (f32x4){0.f,0.f,0.f,0.f}; }
  const unsigned short* abase = xp2 + ((size_t)n*HWPIX + rg*128)*128;
  #pragma unroll
  for(int kc = 0; kc < 4; ++kc){
    bf16x8 af[4], bfr[2];
    #pragma unroll
    for(int mi = 0; mi < 4; ++mi){
      int p = wr*64 + mi*16 + fr;
      af[mi] = *(const bf16x8*)(abase + p*128 + (((kc*4+fq) ^ (p&7))*8));
    }
    #pragma unroll
    for(int nf = 0; nf < 2; ++nf){
      int co = wc*32 + nf*16 + fr;
      int slot = (kc*4 + fq) ^ (co&7);
      bfr[nf] = *(const bf16x8*)(lds + co*256 + slot*16);
    }
    #pragma unroll
    for(int mi = 0; mi < 4; ++mi)
      #pragma unroll
      for(int nf = 0; nf < 2; ++nf)
        acc[mi][nf] = __builtin_amdgcn_mfma_f32_16x16x32_bf16(af[mi], bfr[nf], acc[mi][nf], 0,0,0);
  }
  #pragma unroll
  for(int mi = 0; mi < 4; ++mi)
    #pragma unroll
    for(int nf = 0; nf < 2; ++nf){
      int co = wc*32 + nf*16 + fr;
      int hw = rg*128 + wr*64 + mi*16 + fq*4;
      float nbv = nb[n*64 + co];
      float4 v = { acc[mi][nf][0]+nbv, acc[mi][nf][1]+nbv, acc[mi][nf][2]+nbv, acc[mi][nf][3]+nbv };
      *(float4*)(out + ((size_t)n*64 + co)*HWPIX + hw) = v;
    }
}

// ---------------- host launch ----------------------------------------------
extern "C" void kernel_launch(void* const* d_in, const int* in_sizes, int n_in,
                              void* d_out, int out_size, void* d_ws, size_t ws_size,
                              hipStream_t stream){
  const float* x       = (const float*)d_in[0];
  const int*   ei      = (const int*)d_in[1];
  const float* conf    = (const float*)d_in[2];
  const float* fe_w    = (const float*)d_in[3];
  const float* fe_b    = (const float*)d_in[4];
  const float* fe_g    = (const float*)d_in[5];
  const float* fe_beta = (const float*)d_in[6];
  const float* sp_w1   = (const float*)d_in[7];
  const float* sp_b1   = (const float*)d_in[8];
  const float* sp_g1   = (const float*)d_in[9];
  const float* sp_be1  = (const float*)d_in[10];
  const float* sp_w2   = (const float*)d_in[11];
  const float* sp_b2   = (const float*)d_in[12];
  const float* sp_g2   = (const float*)d_in[13];
  const float* sp_be2  = (const float*)d_in[14];
  const float* g1_lin  = (const float*)d_in[15];
  const float* g1_as   = (const float*)d_in[16];
  const float* g1_ad   = (const float*)d_in[17];
  const float* g1_b    = (const float*)d_in[18];
  const float* g2_lin  = (const float*)d_in[19];
  const float* g2_as   = (const float*)d_in[20];
  const float* g2_ad   = (const float*)d_in[21];
  const float* g2_b    = (const float*)d_in[22];
  const float* op_w    = (const float*)d_in[23];
  const float* op_b    = (const float*)d_in[24];
  float* out = (float*)d_out;

  char* ws = (char*)d_ws;
  size_t off = 0;
  auto alloc = [&](size_t bytes)->char*{
    char* p = ws + off; off += (bytes + 255) & ~(size_t)255; return p;
  };
  unsigned short* bigA  = (unsigned short*)alloc((size_t)NIMG*PPIX*128*2); // xe_pad, later xp2
  unsigned short* xp1   = (unsigned short*)alloc((size_t)NIMG*PPIX*128*2);
  unsigned short* Wb1   = (unsigned short*)alloc(147456*2);
  unsigned short* Wb2   = (unsigned short*)alloc(147456*2);
  unsigned short* Wfe   = (unsigned short*)alloc(8192*2);
  unsigned short* Wop   = (unsigned short*)alloc(8192*2);
  float* xnode_acc = (float*)alloc(NIMG*HIDC*4);
  float* h     = (float*)alloc((size_t)NIMG*512*4);
  float* a_s   = (float*)alloc(NIMG*4*4);
  float* a_d   = (float*)alloc(NIMG*4*4);
  float* xg1   = (float*)alloc(NIMG*HIDC*4);
  float* xg2   = (float*)alloc(NIMG*HIDC*4);
  int* cnt     = (int*)alloc(NIMG*4);
  int* pos     = (int*)alloc(NIMG*4);
  int* offs    = (int*)alloc((NIMG+1)*4);
  int* csr_src = (int*)alloc((NEDGE+NIMG)*4);
  float* nb    = (float*)alloc(NIMG*64*4);
  if(off > ws_size) return;   // workspace too small — bail cleanly
  unsigned short* xp2 = bigA; // reuse region A after conv1 consumed xe

  // 152576 B dynamic LDS for k_conv3 (A 87040 + W dbuf 65536); 1 block/CU.
  hipFuncSetAttribute((const void*)k_conv3,
                      hipFuncAttributeMaxDynamicSharedMemorySize, 152576);

  k_init<<<1024, 256, 0, stream>>>(bigA, xp1, xnode_acc, cnt, pos);
  k_wconv<<<576, 256, 0, stream>>>(sp_w1, sp_w2, fe_w, op_w, Wb1, Wb2, Wfe, Wop);
  k_csr_count<<<(NEDGE+255)/256, 256, 0, stream>>>(ei, cnt);
  k_csr_scan<<<1, 512, 0, stream>>>(cnt, offs);
  k_csr_fill<<<(NEDGE+NIMG+255)/256, 256, 0, stream>>>(ei, offs, pos, csr_src);
  k_encode<<<4096, 256, 0, stream>>>(x, conf, Wfe, fe_b, fe_g, fe_beta, bigA);
  k_conv3<<<2048, 512, 152576, stream>>>(bigA, Wb1, sp_b1, sp_g1, sp_be1, xp1, xnode_acc, 0);
  k_conv3<<<2048, 512, 152576, stream>>>(xp1, Wb2, sp_b2, sp_g2, sp_be2, xp2, xnode_acc, 1);
  k_gat_lin<<<512, 256, 0, stream>>>(xnode_acc, 1.f/1024.f, g1_lin, g1_as, g1_ad, h, a_s, a_d);
  k_gat_aggr<<<512, 256, 0, stream>>>(offs, csr_src, a_s, a_d, h, g1_b, xg1);
  k_gat_lin<<<512, 256, 0, stream>>>(xg1, 1.f, g2_lin, g2_as, g2_ad, h, a_s, a_d);
  k_gat_aggr<<<512, 256, 0, stream>>>(offs, csr_src, a_s, a_d, h, g2_b, xg2);
  k_nodebias<<<(NIMG*64+255)/256, 256, 0, stream>>>(xg2, op_w, op_b, nb);
  k_outconv<<<4096, 256, 0, stream>>>(xp2, Wop, nb, out);
}